// Round 3
// baseline (556.769 us; speedup 1.0000x reference)
//
#include <hip/hip_runtime.h>
#include <stdint.h>

#define NB 4096
#define NT 200
#define NE 64
// attention: 4E=256 -> 64 -> 32 -> 1 ; final MLP: 272 -> 256 -> 128 -> 1
//
// ABI (proven R2-R10): identity order, fp32 floats, int32 ints, FP32 output.
//
// R16: fix the VGPR budget (launch_bounds arg is effectively HALVED).
//  - Empirical across R13/R14/R15: VGPR_Count == 512/(2*declared_min_waves)
//    (84@3, 120@2, 128@2). Every kernel so far spilled: R13's mystery
//    119MB WRITE_SIZE was kvec spill; R15's 233MB was k0/k1 spill.
//  - Now: __launch_bounds__(128, 1) -> empirical budget 256 VGPR. The
//    2-t-per-lane structure needs ~230 live -> fits, no scratch.
//    2 waves/SIMD; LDS-broadcast instrs stay halved vs R13.
//  - din_mlp: 8 rows/block (grid 512, 2 blk/CU vs 1) + TRANSPOSED LDS
//    activations [k][r]: 2 broadcast b128 + 8 FMA per k instead of
//    16 scalar b32. Weight refetch x2 but L2-resident (~4us).

// compile-time component access into a float4[16] register array
#define C4(v, i) (((i)&3)==0 ? v[(i)>>2].x : ((i)&3)==1 ? v[(i)>>2].y : \
                  ((i)&3)==2 ? v[(i)>>2].z : v[(i)>>2].w)

#define BF_STAGE(S)                                                        \
    {                                                                      \
        const bool hi = (j & (S)) != 0;                                    \
        _Pragma("unroll")                                                  \
        for (int i = 0; i < (S); ++i) {                                    \
            const float snd = hi ? C4(k0, i) : C4(k0, i + (S));            \
            const float rec = __shfl_xor(snd, (S), 64);                    \
            C4(k0, i) = (hi ? C4(k0, i + (S)) : C4(k0, i)) + rec;          \
        }                                                                  \
    }

struct __align__(16) SmemA {
    float weffT[64 * 72];   // [j][e], e padded 64->72 (288B rows, 16B-aligned)
    float w2[64 * 32];      // [j][o]
    float q[64];
    float biasj[64];
    float b2[32];
    float wo[32];
    float ip[2 * 64];       // bias partials, later interest partials
    float red_a[2];
    float red_b[2];
};                           // 27.9 KB

__global__ __launch_bounds__(128, 1)
void din_attn(const int* __restrict__ target_item,
              const int* __restrict__ history_items,
              const int* __restrict__ history_mask,
              const int* __restrict__ sparse_features,
              const float* __restrict__ dense_features,
              const float* __restrict__ item_table,
              const float* __restrict__ user_table,
              const float* __restrict__ ctx_table,
              const float* __restrict__ att_w1,
              const float* __restrict__ att_b1,
              const float* __restrict__ att_w2,
              const float* __restrict__ att_b2,
              const float* __restrict__ att_wo,
              const float* __restrict__ att_bo,
              float* __restrict__ mlp_in)   // [NB][272]
{
    __shared__ SmemA sm;

    const int b   = blockIdx.x;
    const int tid = threadIdx.x;    // 0..127
    const int j   = tid & 63;
    const int wv  = tid >> 6;       // 0..1
    const int t0  = tid;            // always < 200
    const int t1  = tid + 128;
    const bool act1 = (t1 < NT);

    // ---- issue own-key loads FIRST (registers; overlap all staging) -----
    const int hrow0 = history_items[(size_t)b * NT + t0];
    const int hrow1 = history_items[(size_t)b * NT + (act1 ? t1 : 0)];
    float4 k0[16], k1[16];
    {
        const float4* rp0 = (const float4*)(item_table + (size_t)hrow0 * NE);
        const float4* rp1 = (const float4*)(item_table + (size_t)hrow1 * NE);
#pragma unroll
        for (int i = 0; i < 16; ++i) { k0[i] = rp0[i]; k1[i] = rp1[i]; }
    }

    // ---- stage small shared data ----------------------------------------
    if (tid < NE) sm.q[tid] = item_table[(size_t)target_item[b] * NE + tid];
    for (int i = tid; i < 512; i += 128)
        ((float4*)sm.w2)[i] = ((const float4*)att_w2)[i];
    if (tid < 32) { sm.b2[tid] = att_b2[tid]; sm.wo[tid] = att_wo[tid]; }
    const float bo = att_bo[0];
    __syncthreads();

    // ---- W_eff^T[j][e] + bias partials (thread = (wv, j), 32 e's) -------
    // attn_in = [k, q, k-q, k*q] @ w1 factorizes (q row-constant):
    // h1[j] = relu( sum_e k_e*(w1[e,j]+w1[128+e,j]+q_e*w1[192+e,j])
    //              + b1[j] + sum_e q_e*(w1[64+e,j]-w1[128+e,j]) )
    {
        float pb = 0.f;
        for (int e = wv; e < NE; e += 2) {
            const float qe = sm.q[e];
            const float A  = att_w1[(size_t)(e)       * NE + j];
            const float Bv = att_w1[(size_t)(64 + e)  * NE + j];
            const float C  = att_w1[(size_t)(128 + e) * NE + j];
            const float D  = att_w1[(size_t)(192 + e) * NE + j];
            sm.weffT[j * 72 + e] = A + C + qe * D;
            pb += qe * (Bv - C);
        }
        sm.ip[wv * 64 + j] = pb;
    }
    __syncthreads();
    if (tid < NE)
        sm.biasj[tid] = att_b1[tid] + sm.ip[tid] + sm.ip[64 + tid];
    __syncthreads();

    // ---- main loop: each weight broadcast feeds BOTH t pipelines --------
    float h2a[32], h2b[32];
#pragma unroll
    for (int o = 0; o < 32; ++o) { h2a[o] = 0.f; h2b[o] = 0.f; }

    for (int jj = 0; jj < 64; ++jj) {
        const float4* wrow = (const float4*)(sm.weffT + jj * 72);  // broadcast
        float a0 = 0.f, a1 = 0.f, a2 = 0.f, a3 = 0.f;
        float b0 = 0.f, b1v = 0.f, b2v = 0.f, b3 = 0.f;
#pragma unroll
        for (int g = 0; g < 16; g += 4) {
            const float4 w0 = wrow[g + 0];
            const float4 w1 = wrow[g + 1];
            const float4 w2v = wrow[g + 2];
            const float4 w3 = wrow[g + 3];
            a0 += w0.x * k0[g + 0].x; b0 += w0.x * k1[g + 0].x;
            a0 += w0.y * k0[g + 0].y; b0 += w0.y * k1[g + 0].y;
            a0 += w0.z * k0[g + 0].z; b0 += w0.z * k1[g + 0].z;
            a0 += w0.w * k0[g + 0].w; b0 += w0.w * k1[g + 0].w;
            a1 += w1.x * k0[g + 1].x; b1v += w1.x * k1[g + 1].x;
            a1 += w1.y * k0[g + 1].y; b1v += w1.y * k1[g + 1].y;
            a1 += w1.z * k0[g + 1].z; b1v += w1.z * k1[g + 1].z;
            a1 += w1.w * k0[g + 1].w; b1v += w1.w * k1[g + 1].w;
            a2 += w2v.x * k0[g + 2].x; b2v += w2v.x * k1[g + 2].x;
            a2 += w2v.y * k0[g + 2].y; b2v += w2v.y * k1[g + 2].y;
            a2 += w2v.z * k0[g + 2].z; b2v += w2v.z * k1[g + 2].z;
            a2 += w2v.w * k0[g + 2].w; b2v += w2v.w * k1[g + 2].w;
            a3 += w3.x * k0[g + 3].x; b3 += w3.x * k1[g + 3].x;
            a3 += w3.y * k0[g + 3].y; b3 += w3.y * k1[g + 3].y;
            a3 += w3.z * k0[g + 3].z; b3 += w3.z * k1[g + 3].z;
            a3 += w3.w * k0[g + 3].w; b3 += w3.w * k1[g + 3].w;
        }
        const float bias = sm.biasj[jj];
        const float h1a = fmaxf(((a0 + a1) + (a2 + a3)) + bias, 0.f);
        const float h1b = fmaxf(((b0 + b1v) + (b2v + b3)) + bias, 0.f);

        const float4* w2row = (const float4*)(sm.w2 + jj * 32);    // broadcast
#pragma unroll
        for (int o4 = 0; o4 < 8; ++o4) {
            const float4 ww = w2row[o4];
            h2a[4 * o4 + 0] += h1a * ww.x;  h2b[4 * o4 + 0] += h1b * ww.x;
            h2a[4 * o4 + 1] += h1a * ww.y;  h2b[4 * o4 + 1] += h1b * ww.y;
            h2a[4 * o4 + 2] += h1a * ww.z;  h2b[4 * o4 + 2] += h1b * ww.z;
            h2a[4 * o4 + 3] += h1a * ww.w;  h2b[4 * o4 + 3] += h1b * ww.w;
        }
    }

    // ---- L3 scores for both t's -----------------------------------------
    float sa = 0.f, sb = 0.f;
#pragma unroll
    for (int o = 0; o < 32; ++o) {
        const float bb = sm.b2[o], wwo = sm.wo[o];
        sa += fmaxf(h2a[o] + bb, 0.f) * wwo;
        sb += fmaxf(h2b[o] + bb, 0.f) * wwo;
    }
    const float scr0 = sa + bo;
    const float scr1 = sb + bo;
    const int mk0 = history_mask[(size_t)b * NT + t0];
    const int mk1 = act1 ? history_mask[(size_t)b * NT + t1] : 0;
    const float v0 = (mk0 != 0) ? scr0 : -1e9f;
    const float v1 = act1 ? ((mk1 != 0) ? scr1 : -1e9f) : -INFINITY;

    // ---- softmax over 256 slots (2 waves x 2 per lane) ------------------
    float m = fmaxf(v0, v1);
#pragma unroll
    for (int s = 32; s; s >>= 1) m = fmaxf(m, __shfl_xor(m, s));
    if (j == 0) sm.red_a[wv] = m;
    __syncthreads();
    const float mx = fmaxf(sm.red_a[0], sm.red_a[1]);
    const float ex0 = __expf(v0 - mx);   // -inf -> 0
    const float ex1 = __expf(v1 - mx);
    float ssum = ex0 + ex1;
#pragma unroll
    for (int s = 32; s; s >>= 1) ssum += __shfl_xor(ssum, s);
    if (j == 0) sm.red_b[wv] = ssum;
    __syncthreads();
    const float total = sm.red_b[0] + sm.red_b[1];
    const float w0s = ex0 / total;
    const float w1s = ex1 / total;

    // ---- interest: combine own 2 rows, butterfly transpose-reduce -------
#pragma unroll
    for (int i = 0; i < 64; ++i)
        C4(k0, i) = C4(k0, i) * w0s + C4(k1, i) * w1s;
    BF_STAGE(32)
    BF_STAGE(16)
    BF_STAGE(8)
    BF_STAGE(4)
    BF_STAGE(2)
    BF_STAGE(1)
    // lane j now holds this wave's partial interest for e = j
    sm.ip[wv * 64 + j] = k0[0].x;
    __syncthreads();

    // ---- assemble mlp_in row [user, ctx, q, interest, dense] ------------
    float* row = mlp_in + (size_t)b * 272;
    if (tid < NE) {
        const float inter = sm.ip[tid] + sm.ip[64 + tid];
        row[0 + tid]   = user_table[(size_t)sparse_features[b * 2 + 0] * NE + tid];
        row[64 + tid]  = ctx_table[(size_t)sparse_features[b * 2 + 1] * NE + tid];
        row[128 + tid] = sm.q[tid];
        row[192 + tid] = inter;
    } else if (tid >= 64 && tid < 80) {
        row[256 + (tid - 64)] = dense_features[(size_t)b * 16 + (tid - 64)];
    }
}

// ---------------------------------------------------------------------------
// Kernel 2: final MLP 272 -> 256 -> 128 -> 1, 8 rows/block (grid 512,
// 2 blocks/CU) with TRANSPOSED LDS activations: per k-step 2 broadcast
// ds_read_b128 + 8 FMA instead of 16 scalar ds_read_b32.
// ---------------------------------------------------------------------------
#define MR 8
__global__ __launch_bounds__(256)
void din_mlp(const float* __restrict__ mlp_in,
             const float* __restrict__ w1,
             const float* __restrict__ b1,
             const float* __restrict__ w2,
             const float* __restrict__ b2,
             const float* __restrict__ ow,
             const float* __restrict__ ob,
             float* __restrict__ out)
{
    __shared__ float inT[272 * MR];     // [k][r]
    __shared__ float h1T[256 * MR];     // [k][r]
    __shared__ float p2[2 * MR * 128];
    __shared__ float h2_lds[MR * 128];

    const int b0  = blockIdx.x * MR;
    const int tid = threadIdx.x;

    // stage transposed: coalesced global read, scattered LDS write
    for (int i = tid; i < MR * 272; i += 256) {
        const int r = i / 272, k = i - 272 * r;
        inT[k * MR + r] = mlp_in[(size_t)b0 * 272 + i];
    }
    __syncthreads();

    // layer 1: 272 -> 256 (thread = col, MR rows via 2 b128 broadcasts/k)
    {
        const float bias = b1[tid];
        float acc[MR];
#pragma unroll
        for (int r = 0; r < MR; ++r) acc[r] = bias;
        const float4* iT = (const float4*)inT;
        for (int k = 0; k < 272; ++k) {
            const float wv = w1[(size_t)k * 256 + tid];
            const float4 i0 = iT[2 * k + 0];
            const float4 i1 = iT[2 * k + 1];
            acc[0] += i0.x * wv; acc[1] += i0.y * wv;
            acc[2] += i0.z * wv; acc[3] += i0.w * wv;
            acc[4] += i1.x * wv; acc[5] += i1.y * wv;
            acc[6] += i1.z * wv; acc[7] += i1.w * wv;
        }
        float4 o0, o1;
        o0.x = fmaxf(acc[0], 0.f); o0.y = fmaxf(acc[1], 0.f);
        o0.z = fmaxf(acc[2], 0.f); o0.w = fmaxf(acc[3], 0.f);
        o1.x = fmaxf(acc[4], 0.f); o1.y = fmaxf(acc[5], 0.f);
        o1.z = fmaxf(acc[6], 0.f); o1.w = fmaxf(acc[7], 0.f);
        ((float4*)h1T)[2 * tid + 0] = o0;   // h1T[k=tid][r] contiguous
        ((float4*)h1T)[2 * tid + 1] = o1;
    }
    __syncthreads();

    // layer 2: 256 -> 128, split-K over two half-blocks
    {
        const int o = tid & 127, half = tid >> 7;
        float acc[MR];
#pragma unroll
        for (int r = 0; r < MR; ++r) acc[r] = 0.f;
        const float4* hT = (const float4*)h1T;
        for (int kk = 0; kk < 128; ++kk) {
            const int k = half * 128 + kk;
            const float wv = w2[(size_t)k * 128 + o];
            const float4 h0 = hT[2 * k + 0];
            const float4 h1v = hT[2 * k + 1];
            acc[0] += h0.x * wv; acc[1] += h0.y * wv;
            acc[2] += h0.z * wv; acc[3] += h0.w * wv;
            acc[4] += h1v.x * wv; acc[5] += h1v.y * wv;
            acc[6] += h1v.z * wv; acc[7] += h1v.w * wv;
        }
#pragma unroll
        for (int r = 0; r < MR; ++r) p2[(half * MR + r) * 128 + o] = acc[r];
    }
    __syncthreads();
    if (tid < 128) {
        const float bias = b2[tid];
#pragma unroll
        for (int r = 0; r < MR; ++r)
            h2_lds[r * 128 + tid] =
                fmaxf(p2[r * 128 + tid] + p2[(MR + r) * 128 + tid] + bias, 0.f);
    }
    __syncthreads();

    // layer 3: 128 -> 1 (16 lanes per row)
    if (tid < 16 * MR) {
        const int r = tid >> 4, l = tid & 15;
        float a = 0.f;
#pragma unroll
        for (int kk = 0; kk < 8; ++kk) {
            const int k = l * 8 + kk;
            a += h2_lds[r * 128 + k] * ow[k];
        }
        a += __shfl_xor(a, 8, 16);
        a += __shfl_xor(a, 4, 16);
        a += __shfl_xor(a, 2, 16);
        a += __shfl_xor(a, 1, 16);
        if (l == 0) out[b0 + r] = a + ob[0];
    }
}

// ---------------------------------------------------------------------------
extern "C" void kernel_launch(void* const* d_in, const int* in_sizes, int n_in,
                              void* d_out, int out_size, void* d_ws, size_t ws_size,
                              hipStream_t stream)
{
    float* mlp_in = (float*)d_ws;   // 4096*272*4 = 4.46 MB

    din_attn<<<NB, 128, 0, stream>>>(
        (const int*)d_in[0],      // target_item
        (const int*)d_in[1],      // history_items
        (const int*)d_in[2],      // history_mask
        (const int*)d_in[3],      // sparse_features
        (const float*)d_in[4],    // dense_features
        (const float*)d_in[5],    // item_table
        (const float*)d_in[6],    // user_table
        (const float*)d_in[7],    // ctx_table
        (const float*)d_in[8],  (const float*)d_in[9],   // att_w1, att_b1
        (const float*)d_in[10], (const float*)d_in[11],  // att_w2, att_b2
        (const float*)d_in[12], (const float*)d_in[13],  // att_wo, att_bo
        mlp_in);

    din_mlp<<<NB / MR, 256, 0, stream>>>(
        mlp_in,
        (const float*)d_in[14], (const float*)d_in[15],  // mlp_w1, mlp_b1
        (const float*)d_in[16], (const float*)d_in[17],  // mlp_w2, mlp_b2
        (const float*)d_in[18], (const float*)d_in[19],  // out_w, out_b
        (float*)d_out);
}

// Round 5
// 456.246 us; speedup vs baseline: 1.2203x; 1.2203x over previous
//
#include <hip/hip_runtime.h>
#include <stdint.h>

#define NB 4096
#define NT 200
#define NE 64
// attention: 4E=256 -> 64 -> 32 -> 1 ; final MLP: 272 -> 256 -> 128 -> 1
//
// ABI (proven R2-R10): identity order, fp32 floats, int32 ints, FP32 output.
//
// R18 == R17 resubmit (round 4 was an infra failure, kernel never ran).
//  - Occupancy via amdgpu_waves_per_eu, not launch_bounds min-waves.
//  - Empirical model: __launch_bounds__(_,N) gives arch-VGPR budget
//    512/(2N) and lets the allocator burn AGPRs (unified file) so total
//    regs/wave can exceed it: R16 had 192 arch + ~150 acc -> 1 wave/SIMD,
//    459us (latency-exposed, VALUBusy 35%).
//  - Now: amdgpu_waves_per_eu(2,4) declares total<=256/wave directly.
//    2-t-per-lane body needs ~230 -> fits, arch-heavy, no scratch,
//    2 waves/SIMD. LDS-broadcast floor ~49K instr/CU ~= 190us.
//  - din_mlp: MR=4 (grid 1024, 4 blk/CU) + unroll-8 so the w1/w2
//    load->FMA chains keep >=8 loads in flight (was latency-bound at
//    2 blk/CU with a serial chain).

// compile-time component access into a float4[16] register array
#define C4(v, i) (((i)&3)==0 ? v[(i)>>2].x : ((i)&3)==1 ? v[(i)>>2].y : \
                  ((i)&3)==2 ? v[(i)>>2].z : v[(i)>>2].w)

#define BF_STAGE(S)                                                        \
    {                                                                      \
        const bool hi = (j & (S)) != 0;                                    \
        _Pragma("unroll")                                                  \
        for (int i = 0; i < (S); ++i) {                                    \
            const float snd = hi ? C4(k0, i) : C4(k0, i + (S));            \
            const float rec = __shfl_xor(snd, (S), 64);                    \
            C4(k0, i) = (hi ? C4(k0, i + (S)) : C4(k0, i)) + rec;          \
        }                                                                  \
    }

struct __align__(16) SmemA {
    float weffT[64 * 72];   // [j][e], e padded 64->72 (288B rows, 16B-aligned)
    float w2[64 * 32];      // [j][o]
    float q[64];
    float biasj[64];
    float b2[32];
    float wo[32];
    float ip[2 * 64];       // bias partials, later interest partials
    float red_a[2];
    float red_b[2];
};                           // 27.9 KB

__global__ __launch_bounds__(128)
__attribute__((amdgpu_waves_per_eu(2, 4)))
void din_attn(const int* __restrict__ target_item,
              const int* __restrict__ history_items,
              const int* __restrict__ history_mask,
              const int* __restrict__ sparse_features,
              const float* __restrict__ dense_features,
              const float* __restrict__ item_table,
              const float* __restrict__ user_table,
              const float* __restrict__ ctx_table,
              const float* __restrict__ att_w1,
              const float* __restrict__ att_b1,
              const float* __restrict__ att_w2,
              const float* __restrict__ att_b2,
              const float* __restrict__ att_wo,
              const float* __restrict__ att_bo,
              float* __restrict__ mlp_in)   // [NB][272]
{
    __shared__ SmemA sm;

    const int b   = blockIdx.x;
    const int tid = threadIdx.x;    // 0..127
    const int j   = tid & 63;
    const int wv  = tid >> 6;       // 0..1
    const int t0  = tid;            // always < 200
    const int t1  = tid + 128;
    const bool act1 = (t1 < NT);

    // ---- issue own-key loads FIRST (registers; overlap all staging) -----
    const int hrow0 = history_items[(size_t)b * NT + t0];
    const int hrow1 = history_items[(size_t)b * NT + (act1 ? t1 : 0)];
    float4 k0[16], k1[16];
    {
        const float4* rp0 = (const float4*)(item_table + (size_t)hrow0 * NE);
        const float4* rp1 = (const float4*)(item_table + (size_t)hrow1 * NE);
#pragma unroll
        for (int i = 0; i < 16; ++i) { k0[i] = rp0[i]; k1[i] = rp1[i]; }
    }

    // ---- stage small shared data ----------------------------------------
    if (tid < NE) sm.q[tid] = item_table[(size_t)target_item[b] * NE + tid];
    for (int i = tid; i < 512; i += 128)
        ((float4*)sm.w2)[i] = ((const float4*)att_w2)[i];
    if (tid < 32) { sm.b2[tid] = att_b2[tid]; sm.wo[tid] = att_wo[tid]; }
    const float bo = att_bo[0];
    __syncthreads();

    // ---- W_eff^T[j][e] + bias partials (thread = (wv, j), 32 e's) -------
    // attn_in = [k, q, k-q, k*q] @ w1 factorizes (q row-constant):
    // h1[j] = relu( sum_e k_e*(w1[e,j]+w1[128+e,j]+q_e*w1[192+e,j])
    //              + b1[j] + sum_e q_e*(w1[64+e,j]-w1[128+e,j]) )
    {
        float pb = 0.f;
        for (int e = wv; e < NE; e += 2) {
            const float qe = sm.q[e];
            const float A  = att_w1[(size_t)(e)       * NE + j];
            const float Bv = att_w1[(size_t)(64 + e)  * NE + j];
            const float C  = att_w1[(size_t)(128 + e) * NE + j];
            const float D  = att_w1[(size_t)(192 + e) * NE + j];
            sm.weffT[j * 72 + e] = A + C + qe * D;
            pb += qe * (Bv - C);
        }
        sm.ip[wv * 64 + j] = pb;
    }
    __syncthreads();
    if (tid < NE)
        sm.biasj[tid] = att_b1[tid] + sm.ip[tid] + sm.ip[64 + tid];
    __syncthreads();

    // ---- main loop: each weight broadcast feeds BOTH t pipelines --------
    float h2a[32], h2b[32];
#pragma unroll
    for (int o = 0; o < 32; ++o) { h2a[o] = 0.f; h2b[o] = 0.f; }

    for (int jj = 0; jj < 64; ++jj) {
        const float4* wrow = (const float4*)(sm.weffT + jj * 72);  // broadcast
        float a0 = 0.f, a1 = 0.f, a2 = 0.f, a3 = 0.f;
        float b0 = 0.f, b1v = 0.f, b2v = 0.f, b3 = 0.f;
#pragma unroll
        for (int g = 0; g < 16; g += 4) {
            const float4 w0 = wrow[g + 0];
            const float4 w1 = wrow[g + 1];
            const float4 w2v = wrow[g + 2];
            const float4 w3 = wrow[g + 3];
            a0 += w0.x * k0[g + 0].x; b0 += w0.x * k1[g + 0].x;
            a0 += w0.y * k0[g + 0].y; b0 += w0.y * k1[g + 0].y;
            a0 += w0.z * k0[g + 0].z; b0 += w0.z * k1[g + 0].z;
            a0 += w0.w * k0[g + 0].w; b0 += w0.w * k1[g + 0].w;
            a1 += w1.x * k0[g + 1].x; b1v += w1.x * k1[g + 1].x;
            a1 += w1.y * k0[g + 1].y; b1v += w1.y * k1[g + 1].y;
            a1 += w1.z * k0[g + 1].z; b1v += w1.z * k1[g + 1].z;
            a1 += w1.w * k0[g + 1].w; b1v += w1.w * k1[g + 1].w;
            a2 += w2v.x * k0[g + 2].x; b2v += w2v.x * k1[g + 2].x;
            a2 += w2v.y * k0[g + 2].y; b2v += w2v.y * k1[g + 2].y;
            a2 += w2v.z * k0[g + 2].z; b2v += w2v.z * k1[g + 2].z;
            a2 += w2v.w * k0[g + 2].w; b2v += w2v.w * k1[g + 2].w;
            a3 += w3.x * k0[g + 3].x; b3 += w3.x * k1[g + 3].x;
            a3 += w3.y * k0[g + 3].y; b3 += w3.y * k1[g + 3].y;
            a3 += w3.z * k0[g + 3].z; b3 += w3.z * k1[g + 3].z;
            a3 += w3.w * k0[g + 3].w; b3 += w3.w * k1[g + 3].w;
        }
        const float bias = sm.biasj[jj];
        const float h1a = fmaxf(((a0 + a1) + (a2 + a3)) + bias, 0.f);
        const float h1b = fmaxf(((b0 + b1v) + (b2v + b3)) + bias, 0.f);

        const float4* w2row = (const float4*)(sm.w2 + jj * 32);    // broadcast
#pragma unroll
        for (int o4 = 0; o4 < 8; ++o4) {
            const float4 ww = w2row[o4];
            h2a[4 * o4 + 0] += h1a * ww.x;  h2b[4 * o4 + 0] += h1b * ww.x;
            h2a[4 * o4 + 1] += h1a * ww.y;  h2b[4 * o4 + 1] += h1b * ww.y;
            h2a[4 * o4 + 2] += h1a * ww.z;  h2b[4 * o4 + 2] += h1b * ww.z;
            h2a[4 * o4 + 3] += h1a * ww.w;  h2b[4 * o4 + 3] += h1b * ww.w;
        }
    }

    // ---- L3 scores for both t's -----------------------------------------
    float sa = 0.f, sb = 0.f;
#pragma unroll
    for (int o = 0; o < 32; ++o) {
        const float bb = sm.b2[o], wwo = sm.wo[o];
        sa += fmaxf(h2a[o] + bb, 0.f) * wwo;
        sb += fmaxf(h2b[o] + bb, 0.f) * wwo;
    }
    const float scr0 = sa + bo;
    const float scr1 = sb + bo;
    const int mk0 = history_mask[(size_t)b * NT + t0];
    const int mk1 = act1 ? history_mask[(size_t)b * NT + t1] : 0;
    const float v0 = (mk0 != 0) ? scr0 : -1e9f;
    const float v1 = act1 ? ((mk1 != 0) ? scr1 : -1e9f) : -INFINITY;

    // ---- softmax over 256 slots (2 waves x 2 per lane) ------------------
    float m = fmaxf(v0, v1);
#pragma unroll
    for (int s = 32; s; s >>= 1) m = fmaxf(m, __shfl_xor(m, s));
    if (j == 0) sm.red_a[wv] = m;
    __syncthreads();
    const float mx = fmaxf(sm.red_a[0], sm.red_a[1]);
    const float ex0 = __expf(v0 - mx);   // -inf -> 0
    const float ex1 = __expf(v1 - mx);
    float ssum = ex0 + ex1;
#pragma unroll
    for (int s = 32; s; s >>= 1) ssum += __shfl_xor(ssum, s);
    if (j == 0) sm.red_b[wv] = ssum;
    __syncthreads();
    const float total = sm.red_b[0] + sm.red_b[1];
    const float w0s = ex0 / total;
    const float w1s = ex1 / total;

    // ---- interest: combine own 2 rows, butterfly transpose-reduce -------
#pragma unroll
    for (int i = 0; i < 64; ++i)
        C4(k0, i) = C4(k0, i) * w0s + C4(k1, i) * w1s;
    BF_STAGE(32)
    BF_STAGE(16)
    BF_STAGE(8)
    BF_STAGE(4)
    BF_STAGE(2)
    BF_STAGE(1)
    // lane j now holds this wave's partial interest for e = j
    sm.ip[wv * 64 + j] = k0[0].x;
    __syncthreads();

    // ---- assemble mlp_in row [user, ctx, q, interest, dense] ------------
    float* row = mlp_in + (size_t)b * 272;
    if (tid < NE) {
        const float inter = sm.ip[tid] + sm.ip[64 + tid];
        row[0 + tid]   = user_table[(size_t)sparse_features[b * 2 + 0] * NE + tid];
        row[64 + tid]  = ctx_table[(size_t)sparse_features[b * 2 + 1] * NE + tid];
        row[128 + tid] = sm.q[tid];
        row[192 + tid] = inter;
    } else if (tid >= 64 && tid < 80) {
        row[256 + (tid - 64)] = dense_features[(size_t)b * 16 + (tid - 64)];
    }
}

// ---------------------------------------------------------------------------
// Kernel 2: final MLP 272 -> 256 -> 128 -> 1, 4 rows/block (grid 1024,
// 4 blocks/CU) with transposed LDS activations (broadcast b128 reads) and
// unroll-8 load pipelining.
// ---------------------------------------------------------------------------
#define MR 4
__global__ __launch_bounds__(256)
void din_mlp(const float* __restrict__ mlp_in,
             const float* __restrict__ w1,
             const float* __restrict__ b1,
             const float* __restrict__ w2,
             const float* __restrict__ b2,
             const float* __restrict__ ow,
             const float* __restrict__ ob,
             float* __restrict__ out)
{
    __shared__ float inT[272 * MR];     // [k][r]
    __shared__ float h1T[256 * MR];     // [k][r]
    __shared__ float p2[2 * MR * 128];
    __shared__ float h2_lds[MR * 128];

    const int b0  = blockIdx.x * MR;
    const int tid = threadIdx.x;

    // stage transposed: coalesced global read, scattered LDS write
    for (int i = tid; i < MR * 272; i += 256) {
        const int r = i / 272, k = i - 272 * r;
        inT[k * MR + r] = mlp_in[(size_t)b0 * 272 + i];
    }
    __syncthreads();

    // layer 1: 272 -> 256 (thread = col, MR rows via 1 b128 broadcast/k)
    {
        const float bias = b1[tid];
        float a0 = bias, a1 = bias, a2 = bias, a3 = bias;
        const float4* iT = (const float4*)inT;
#pragma unroll 8
        for (int k = 0; k < 272; ++k) {
            const float wv = w1[(size_t)k * 256 + tid];
            const float4 iv = iT[k];
            a0 += iv.x * wv; a1 += iv.y * wv;
            a2 += iv.z * wv; a3 += iv.w * wv;
        }
        float4 o;
        o.x = fmaxf(a0, 0.f); o.y = fmaxf(a1, 0.f);
        o.z = fmaxf(a2, 0.f); o.w = fmaxf(a3, 0.f);
        ((float4*)h1T)[tid] = o;        // h1T[k=tid][r] contiguous
    }
    __syncthreads();

    // layer 2: 256 -> 128, split-K over two half-blocks
    {
        const int o = tid & 127, half = tid >> 7;
        float c0 = 0.f, c1 = 0.f, c2 = 0.f, c3 = 0.f;
        const float4* hT = (const float4*)h1T;
#pragma unroll 8
        for (int kk = 0; kk < 128; ++kk) {
            const int k = half * 128 + kk;
            const float wv = w2[(size_t)k * 128 + o];
            const float4 hv = hT[k];
            c0 += hv.x * wv; c1 += hv.y * wv;
            c2 += hv.z * wv; c3 += hv.w * wv;
        }
        p2[(half * MR + 0) * 128 + o] = c0;
        p2[(half * MR + 1) * 128 + o] = c1;
        p2[(half * MR + 2) * 128 + o] = c2;
        p2[(half * MR + 3) * 128 + o] = c3;
    }
    __syncthreads();
    if (tid < 128) {
        const float bias = b2[tid];
#pragma unroll
        for (int r = 0; r < MR; ++r)
            h2_lds[r * 128 + tid] =
                fmaxf(p2[r * 128 + tid] + p2[(MR + r) * 128 + tid] + bias, 0.f);
    }
    __syncthreads();

    // layer 3: 128 -> 1 (16 lanes per row)
    if (tid < 16 * MR) {
        const int r = tid >> 4, l = tid & 15;
        float a = 0.f;
#pragma unroll
        for (int kk = 0; kk < 8; ++kk) {
            const int k = l * 8 + kk;
            a += h2_lds[r * 128 + k] * ow[k];
        }
        a += __shfl_xor(a, 8, 16);
        a += __shfl_xor(a, 4, 16);
        a += __shfl_xor(a, 2, 16);
        a += __shfl_xor(a, 1, 16);
        if (l == 0) out[b0 + r] = a + ob[0];
    }
}

// ---------------------------------------------------------------------------
extern "C" void kernel_launch(void* const* d_in, const int* in_sizes, int n_in,
                              void* d_out, int out_size, void* d_ws, size_t ws_size,
                              hipStream_t stream)
{
    float* mlp_in = (float*)d_ws;   // 4096*272*4 = 4.46 MB

    din_attn<<<NB, 128, 0, stream>>>(
        (const int*)d_in[0],      // target_item
        (const int*)d_in[1],      // history_items
        (const int*)d_in[2],      // history_mask
        (const int*)d_in[3],      // sparse_features
        (const float*)d_in[4],    // dense_features
        (const float*)d_in[5],    // item_table
        (const float*)d_in[6],    // user_table
        (const float*)d_in[7],    // ctx_table
        (const float*)d_in[8],  (const float*)d_in[9],   // att_w1, att_b1
        (const float*)d_in[10], (const float*)d_in[11],  // att_w2, att_b2
        (const float*)d_in[12], (const float*)d_in[13],  // att_wo, att_bo
        mlp_in);

    din_mlp<<<NB / MR, 256, 0, stream>>>(
        mlp_in,
        (const float*)d_in[14], (const float*)d_in[15],  // mlp_w1, mlp_b1
        (const float*)d_in[16], (const float*)d_in[17],  // mlp_w2, mlp_b2
        (const float*)d_in[18], (const float*)d_in[19],  // out_w, out_b
        (float*)d_out);
}